// Round 2
// baseline (271.468 us; speedup 1.0000x reference)
//
#include <hip/hip_runtime.h>
#include <math.h>

#define B_ 512
#define V_ 50000
#define D_ 512
#define T_ 4
#define P_ 16
#define L_ 8
#define OUT_ 300

// ---------------------------------------------------------------------------
// K1: per (b,i,t) block. 128 dots s[p][l] = <node_emb, feature_emb[p][l]>,
// argmax_p of row-sums (first-max), masked softmax over L of the best path,
// then compute this t's PARTIAL context in-block (selected rows are cache-hot)
// and write 512 floats to pcon[g].
// ---------------------------------------------------------------------------
__global__ __launch_bounds__(256) void k1_score(
    const int* __restrict__ nodes, const int* __restrict__ features,
    const float* __restrict__ emb,
    const float* __restrict__ v, const float* __restrict__ w_rp,
    const float* __restrict__ w_ch, const float* __restrict__ w_on,
    float* __restrict__ pcon)
{
    const int g   = blockIdx.x;        // g = (b*2+i)*T + t
    const int t   = g & (T_ - 1);
    const int bi  = g >> 2;
    const int tid = threadIdx.x;
    const int wid = tid >> 6, lane = tid & 63;

    __shared__ float s_s[P_ * L_];     // 128 dot results
    __shared__ float s_pw[P_];
    __shared__ float s_coef[L_];
    __shared__ int   s_bp;

    const float* nrow = emb + (size_t)nodes[bi] * D_;
    // per-lane node fragment (8 floats), reused for all 32 rows of this wave
    const float4 n0 = *(const float4*)(nrow + lane * 8);
    const float4 n1 = *(const float4*)(nrow + lane * 8 + 4);

    const int featBase = g * (P_ * L_);

    // ---- dot phase: 32 rows per wave, 4 rows per body, 8 rows in flight ----
    #pragma unroll 2
    for (int j = 0; j < 32; j += 4) {
        const int r  = wid * 32 + j;
        const int i0 = features[featBase + r + 0];
        const int i1 = features[featBase + r + 1];
        const int i2 = features[featBase + r + 2];
        const int i3 = features[featBase + r + 3];
        const float* p0 = emb + (size_t)i0 * D_ + lane * 8;
        const float* p1 = emb + (size_t)i1 * D_ + lane * 8;
        const float* p2 = emb + (size_t)i2 * D_ + lane * 8;
        const float* p3 = emb + (size_t)i3 * D_ + lane * 8;
        const float4 a0 = ((const float4*)p0)[0], b0 = ((const float4*)p0)[1];
        const float4 a1 = ((const float4*)p1)[0], b1 = ((const float4*)p1)[1];
        const float4 a2 = ((const float4*)p2)[0], b2 = ((const float4*)p2)[1];
        const float4 a3 = ((const float4*)p3)[0], b3 = ((const float4*)p3)[1];
        float d0 = n0.x*a0.x + n0.y*a0.y + n0.z*a0.z + n0.w*a0.w
                 + n1.x*b0.x + n1.y*b0.y + n1.z*b0.z + n1.w*b0.w;
        float d1 = n0.x*a1.x + n0.y*a1.y + n0.z*a1.z + n0.w*a1.w
                 + n1.x*b1.x + n1.y*b1.y + n1.z*b1.z + n1.w*b1.w;
        float d2 = n0.x*a2.x + n0.y*a2.y + n0.z*a2.z + n0.w*a2.w
                 + n1.x*b2.x + n1.y*b2.y + n1.z*b2.z + n1.w*b2.w;
        float d3 = n0.x*a3.x + n0.y*a3.y + n0.z*a3.z + n0.w*a3.w
                 + n1.x*b3.x + n1.y*b3.y + n1.z*b3.z + n1.w*b3.w;
        #pragma unroll
        for (int off = 32; off; off >>= 1) {
            d0 += __shfl_down(d0, off);
            d1 += __shfl_down(d1, off);
            d2 += __shfl_down(d2, off);
            d3 += __shfl_down(d3, off);
        }
        if (lane == 0) {
            s_s[r + 0] = d0; s_s[r + 1] = d1;
            s_s[r + 2] = d2; s_s[r + 3] = d3;
        }
    }
    __syncthreads();

    // ---- selection ----
    if (tid < P_) {
        float s = 0.f;
        #pragma unroll
        for (int l = 0; l < L_; ++l) s += s_s[tid * L_ + l];
        s_pw[tid] = s;
    }
    __syncthreads();
    if (tid == 0) {
        float best = -1e30f; int bp = 0;
        #pragma unroll
        for (int p = 0; p < P_; ++p)
            if (s_pw[p] > best) { best = s_pw[p]; bp = p; }   // first-max
        float x[L_], m = -1e30f;
        #pragma unroll
        for (int l = 0; l < L_; ++l) {
            const float sv = s_s[bp * L_ + l];
            x[l] = sv + (sv == 0.0f ? -9999.0f : 0.0f);
            m = fmaxf(m, x[l]);
        }
        float e[L_], sum = 0.f;
        #pragma unroll
        for (int l = 0; l < L_; ++l) { e[l] = expf(x[l] - m); sum += e[l]; }
        const float wr = w_rp[0], wc = w_ch[0], wo = w_on[0];
        const float tw = (t == 0) ? wr : (t == 1) ? wc : (t == 2) ? wo
                                       : (1.0f - wr - wc - wo);
        const float inv = 1.0f / sum;
        #pragma unroll
        for (int l = 0; l < L_; ++l) s_coef[l] = tw * v[l] * (e[l] * inv);
        s_bp = bp;
    }
    __syncthreads();

    // ---- partial context for this t (rows are L1/L2-hot) ----
    const int bp = s_bp;
    float c0 = 0.f, c1 = 0.f;
    #pragma unroll
    for (int l = 0; l < L_; ++l) {
        const int   idx = features[featBase + bp * L_ + l];
        const float cf  = s_coef[l];
        const float* row = emb + (size_t)idx * D_;
        c0 += cf * row[tid];
        c1 += cf * row[tid + 256];
    }
    pcon[(size_t)g * 512 + tid]       = c0;
    pcon[(size_t)g * 512 + 256 + tid] = c1;
}

// ---------------------------------------------------------------------------
// K2: per (b,i) block. context = sum of the 4 partial contexts;
// contextual = [node_emb | context] (1024 floats). Pure streaming.
// ---------------------------------------------------------------------------
__global__ __launch_bounds__(256) void k2_merge(
    const int* __restrict__ nodes, const float* __restrict__ emb,
    const float* __restrict__ pcon, float* __restrict__ cont)
{
    const int bi  = blockIdx.x;
    const int tid = threadIdx.x;
    const float* nrow = emb + (size_t)nodes[bi] * D_;
    const float* pc   = pcon + (size_t)bi * 4 * 512;
    const float c0 = pc[tid]       + pc[512 + tid]
                   + pc[1024 + tid] + pc[1536 + tid];
    const float c1 = pc[256 + tid]  + pc[768 + tid]
                   + pc[1280 + tid] + pc[1792 + tid];
    float* cp = cont + (size_t)bi * 1024;
    cp[tid]        = nrow[tid];
    cp[256 + tid]  = nrow[tid + 256];
    cp[512 + tid]  = c0;
    cp[768 + tid]  = c1;
}

// ---------------------------------------------------------------------------
// K3: fused GEMM (contextual @ W_out^T + b_out) + per-b cosine -> sim_ent.
// 4 b's (8 contextual vectors) per block, staged in LDS.
// ---------------------------------------------------------------------------
__global__ __launch_bounds__(256) void k3_gemm_cos(
    const float* __restrict__ cont, const float* __restrict__ W,
    const float* __restrict__ bias, float* __restrict__ out)
{
    const int bb  = blockIdx.x;       // handles b = bb*4 .. bb*4+3
    const int tid = threadIdx.x;
    const int wid = tid >> 6, lane = tid & 63;

    __shared__ float cs[8][1024];     // 32 KB
    __shared__ float red[4][12];

    for (int k = tid; k < 8 * 1024; k += 256) {
        const int vec = k >> 10, d = k & 1023;
        cs[vec][d] = cont[(size_t)(bb * 8 + vec) * 1024 + d];
    }
    __syncthreads();

    float sab[4] = {0,0,0,0}, saa[4] = {0,0,0,0}, sbb[4] = {0,0,0,0};

    for (int o = wid; o < OUT_; o += 4) {
        const float* wrow = W + (size_t)o * 1024;
        float wv[16];
        #pragma unroll
        for (int k = 0; k < 16; ++k) wv[k] = wrow[lane + 64 * k];
        float dot[8];
        #pragma unroll
        for (int vv = 0; vv < 8; ++vv) {
            float acc = 0.f;
            #pragma unroll
            for (int k = 0; k < 16; ++k) acc += wv[k] * cs[vv][lane + 64 * k];
            dot[vv] = acc;
        }
        #pragma unroll
        for (int vv = 0; vv < 8; ++vv) {
            #pragma unroll
            for (int off = 32; off; off >>= 1) dot[vv] += __shfl_down(dot[vv], off);
        }
        if (lane == 0) {
            const float bo = bias[o];
            #pragma unroll
            for (int j = 0; j < 4; ++j) {
                const float r0 = dot[2*j]   + bo;
                const float r1 = dot[2*j+1] + bo;
                sab[j] += r0 * r1; saa[j] += r0 * r0; sbb[j] += r1 * r1;
            }
        }
    }
    if (lane == 0) {
        #pragma unroll
        for (int j = 0; j < 4; ++j) {
            red[wid][j*3+0] = sab[j];
            red[wid][j*3+1] = saa[j];
            red[wid][j*3+2] = sbb[j];
        }
    }
    __syncthreads();
    if (tid < 4) {
        const int j = tid;
        float ab = 0.f, aa = 0.f, bbv = 0.f;
        for (int w2 = 0; w2 < 4; ++w2) {
            ab  += red[w2][j*3+0];
            aa  += red[w2][j*3+1];
            bbv += red[w2][j*3+2];
        }
        const float na = fmaxf(sqrtf(aa),  1e-8f);
        const float nb = fmaxf(sqrtf(bbv), 1e-8f);
        out[bb * 4 + j] = ab / (na * nb);
    }
}

// ---------------------------------------------------------------------------
// K4: property branch. Per b: 6 aggregates (sum of 32 emb rows); one wave
// owns a whole group (waves 0,1 take two groups), float4 loads, agg in LDS,
// then 3 cosines -> sim_prop -> out[B + b].
// ---------------------------------------------------------------------------
__global__ __launch_bounds__(256) void k4_prop(
    const int* __restrict__ pf, const float* __restrict__ emb,
    const float* __restrict__ pw_, const float* __restrict__ dw_,
    float* __restrict__ out)
{
    const int b   = blockIdx.x;
    const int tid = threadIdx.x;
    const int wid = tid >> 6, lane = tid & 63;

    __shared__ float agg[6][512];     // 12 KB
    __shared__ float red[4][9];

    for (int g = wid; g < 6; g += 4) {       // wave0:{0,4} wave1:{1,5} wave2:{2} wave3:{3}
        const int i = g / 3, jj = g % 3;
        const int base = ((b * 2 + i) * 3 + jj) * 32;
        float4 s0 = {0,0,0,0}, s1 = {0,0,0,0};
        #pragma unroll 4
        for (int k = 0; k < 32; ++k) {
            const int idx = pf[base + k];
            const float* row = emb + (size_t)idx * D_;
            const float4 r0 = *(const float4*)(row + lane * 4);
            const float4 r1 = *(const float4*)(row + 256 + lane * 4);
            s0.x += r0.x; s0.y += r0.y; s0.z += r0.z; s0.w += r0.w;
            s1.x += r1.x; s1.y += r1.y; s1.z += r1.z; s1.w += r1.w;
        }
        *(float4*)&agg[g][lane * 4]       = s0;
        *(float4*)&agg[g][256 + lane * 4] = s1;
    }
    __syncthreads();

    float p[9];
    #pragma unroll
    for (int j = 0; j < 3; ++j) {
        const float* A  = agg[j];
        const float* Bv = agg[3 + j];
        const float a0 = A[tid],  a1 = A[tid + 256];
        const float b0 = Bv[tid], b1 = Bv[tid + 256];
        p[j*3+0] = a0 * b0 + a1 * b1;
        p[j*3+1] = a0 * a0 + a1 * a1;
        p[j*3+2] = b0 * b0 + b1 * b1;
    }
    #pragma unroll
    for (int q = 0; q < 9; ++q) {
        #pragma unroll
        for (int off = 32; off; off >>= 1) p[q] += __shfl_down(p[q], off);
    }
    if (lane == 0) {
        #pragma unroll
        for (int q = 0; q < 9; ++q) red[wid][q] = p[q];
    }
    __syncthreads();
    if (tid == 0) {
        float s[9];
        #pragma unroll
        for (int q = 0; q < 9; ++q)
            s[q] = red[0][q] + red[1][q] + red[2][q] + red[3][q];
        float cosv[3];
        #pragma unroll
        for (int j = 0; j < 3; ++j) {
            const float na = fmaxf(sqrtf(s[j*3+1]), 1e-8f);
            const float nb = fmaxf(sqrtf(s[j*3+2]), 1e-8f);
            cosv[j] = s[j*3+0] / (na * nb);
        }
        const float pw = pw_[0], dw = dw_[0];
        out[B_ + b] = pw * cosv[0] + dw * cosv[1] + (1.0f - pw - dw) * cosv[2];
    }
}

// ---------------------------------------------------------------------------
extern "C" void kernel_launch(void* const* d_in, const int* in_sizes, int n_in,
                              void* d_out, int out_size, void* d_ws, size_t ws_size,
                              hipStream_t stream) {
    const int*   nodes   = (const int*)  d_in[0];
    const int*   features= (const int*)  d_in[1];
    // d_in[2] = prop_nodes (unused by reference)
    const int*   propf   = (const int*)  d_in[3];
    const float* emb     = (const float*)d_in[4];
    const float* W_out   = (const float*)d_in[5];
    const float* b_out   = (const float*)d_in[6];
    const float* v       = (const float*)d_in[7];
    const float* w_rp    = (const float*)d_in[8];
    const float* w_ch    = (const float*)d_in[9];
    const float* w_on    = (const float*)d_in[10];
    const float* pw      = (const float*)d_in[11];
    const float* dw      = (const float*)d_in[12];
    float* out = (float*)d_out;

    // workspace layout: pcon 4096*512 f32 (8 MB) | cont 1024*1024 f32 (4 MB)
    char* ws = (char*)d_ws;
    float* pcon = (float*)ws;
    float* cont = (float*)(ws + (size_t)4096 * 512 * sizeof(float));

    k1_score<<<B_ * 2 * T_, 256, 0, stream>>>(nodes, features, emb, v,
                                              w_rp, w_ch, w_on, pcon);
    k2_merge<<<B_ * 2, 256, 0, stream>>>(nodes, emb, pcon, cont);
    k3_gemm_cos<<<B_ / 4, 256, 0, stream>>>(cont, W_out, b_out, out);
    k4_prop<<<B_, 256, 0, stream>>>(propf, emb, pw, dw, out);
}

// Round 3
// 245.945 us; speedup vs baseline: 1.1038x; 1.1038x over previous
//
#include <hip/hip_runtime.h>
#include <math.h>

#define B_ 512
#define V_ 50000
#define D_ 512
#define T_ 4
#define P_ 16
#define L_ 8
#define OUT_ 300
#define NBI 1024            // B*2
#define NG  4096            // B*2*T
#define NSLOT 524288        // NG*128 (= B*2*T*P*L)
#define NSCAN 196           // ceil(V/256)

// ---------------------------------------------------------------------------
// KN: gather the 1024 node vectors into a contiguous, L2-friendly table.
// ---------------------------------------------------------------------------
__global__ __launch_bounds__(256) void kn_nodes(
    const int* __restrict__ nodes, const float* __restrict__ emb,
    float* __restrict__ narr)
{
    const int bi = blockIdx.x, tid = threadIdx.x;
    const float2 r = *(const float2*)(emb + (size_t)nodes[bi] * D_ + 2 * tid);
    *(float2*)(narr + (size_t)bi * D_ + 2 * tid) = r;
}

// ---------------------------------------------------------------------------
// KA: histogram of feature vocab rows (int atomics -> deterministic counts).
// ---------------------------------------------------------------------------
__global__ __launch_bounds__(256) void ka_hist(
    const int* __restrict__ features, int* __restrict__ counts)
{
    const int slot = blockIdx.x * 256 + threadIdx.x;
    atomicAdd(&counts[features[slot]], 1);
}

// KB1: per-256-chunk sums of counts.
__global__ __launch_bounds__(256) void kb1_bsum(
    const int* __restrict__ counts, int* __restrict__ bsum)
{
    const int tid = threadIdx.x, v = blockIdx.x * 256 + tid;
    const int wid = tid >> 6, lane = tid & 63;
    __shared__ int red[4];
    int c = (v < V_) ? counts[v] : 0;
    #pragma unroll
    for (int off = 32; off; off >>= 1) c += __shfl_down(c, off);
    if (lane == 0) red[wid] = c;
    __syncthreads();
    if (tid == 0) bsum[blockIdx.x] = red[0] + red[1] + red[2] + red[3];
}

// KB2: exclusive scan of the 196 chunk sums (single block).
__global__ __launch_bounds__(256) void kb2_scan(
    const int* __restrict__ bsum, int* __restrict__ bbase)
{
    const int tid = threadIdx.x;
    __shared__ int sc[256];
    const int x = (tid < NSCAN) ? bsum[tid] : 0;
    sc[tid] = x;
    __syncthreads();
    for (int off = 1; off < 256; off <<= 1) {
        const int y = (tid >= off) ? sc[tid - off] : 0;
        __syncthreads();
        sc[tid] += y;
        __syncthreads();
    }
    if (tid < NSCAN) bbase[tid] = sc[tid] - x;   // exclusive
}

// KB3: full exclusive offsets; writes offsets[] and cursor[].
__global__ __launch_bounds__(256) void kb3_offsets(
    const int* __restrict__ counts, const int* __restrict__ bbase,
    int* __restrict__ offs, int* __restrict__ cursor)
{
    const int tid = threadIdx.x, v = blockIdx.x * 256 + tid;
    __shared__ int sc[256];
    const int c = (v < V_) ? counts[v] : 0;
    sc[tid] = c;
    __syncthreads();
    for (int off = 1; off < 256; off <<= 1) {
        const int y = (tid >= off) ? sc[tid - off] : 0;
        __syncthreads();
        sc[tid] += y;
        __syncthreads();
    }
    const int o = bbase[blockIdx.x] + sc[tid] - c;
    if (v < V_) { offs[v] = o; cursor[v] = o; }
    if (v == V_ - 1) offs[V_] = o + c;
}

// KC: scatter slot ids into row-sorted order.
__global__ __launch_bounds__(256) void kc_scatter(
    const int* __restrict__ features, int* __restrict__ cursor,
    int* __restrict__ inv)
{
    const int slot = blockIdx.x * 256 + threadIdx.x;
    const int row  = features[slot];
    const int pos  = atomicAdd(&cursor[row], 1);
    inv[pos] = slot;
}

// ---------------------------------------------------------------------------
// KD: stream emb once; one wave per vocab row; dot against referenced node
// vectors (L2-resident narr); scatter scalar scores to dense s[slot].
// ---------------------------------------------------------------------------
__global__ __launch_bounds__(256) void kd_dots(
    const float* __restrict__ emb, const float* __restrict__ narr,
    const int* __restrict__ offs, const int* __restrict__ inv,
    float* __restrict__ sarr)
{
    const int tid = threadIdx.x;
    const int wid = tid >> 6, lane = tid & 63;
    const int row = blockIdx.x * 4 + wid;          // 12500*4 = 50000 exact

    const float* rp = emb + (size_t)row * D_ + lane * 8;
    const float4 r0 = ((const float4*)rp)[0];
    const float4 r1 = ((const float4*)rp)[1];

    const int st = offs[row], en = offs[row + 1];
    for (int e = st; e < en; e += 2) {
        const int s0 = inv[e];
        const int s1 = (e + 1 < en) ? inv[e + 1] : -1;
        const float* q0 = narr + (size_t)(s0 >> 9) * D_ + lane * 8;
        const float4 a0 = ((const float4*)q0)[0];
        const float4 a1 = ((const float4*)q0)[1];
        float d0 = r0.x*a0.x + r0.y*a0.y + r0.z*a0.z + r0.w*a0.w
                 + r1.x*a1.x + r1.y*a1.y + r1.z*a1.z + r1.w*a1.w;
        float d1 = 0.f;
        if (s1 >= 0) {
            const float* q1 = narr + (size_t)(s1 >> 9) * D_ + lane * 8;
            const float4 b0 = ((const float4*)q1)[0];
            const float4 b1 = ((const float4*)q1)[1];
            d1 = r0.x*b0.x + r0.y*b0.y + r0.z*b0.z + r0.w*b0.w
               + r1.x*b1.x + r1.y*b1.y + r1.z*b1.z + r1.w*b1.w;
        }
        #pragma unroll
        for (int off = 32; off; off >>= 1) {
            d0 += __shfl_down(d0, off);
            d1 += __shfl_down(d1, off);
        }
        if (lane == 0) {
            sarr[s0] = d0;
            if (s1 >= 0) sarr[s1] = d1;
        }
    }
}

// ---------------------------------------------------------------------------
// KE: per g=(bi,t): argmax over P of path sums (first-max), masked softmax
// over L, emit 8 selected row indices + fused coefficients.
// ---------------------------------------------------------------------------
__global__ __launch_bounds__(256) void ke_select(
    const float* __restrict__ sarr, const int* __restrict__ features,
    const float* __restrict__ v, const float* __restrict__ w_rp,
    const float* __restrict__ w_ch, const float* __restrict__ w_on,
    int* __restrict__ wsIdx, float* __restrict__ wsCoef)
{
    const int tid = threadIdx.x;
    const int wid = tid >> 6, lane = tid & 63;
    const int g = blockIdx.x * 4 + wid;
    const int t = g & (T_ - 1);

    // lanes 0..15: pw[p] = sum of 8 scores
    float bv = -1e30f; int bix = 0x7fffffff;
    if (lane < P_) {
        const float* sp = sarr + (size_t)g * 128 + lane * 8;
        const float4 x0 = ((const float4*)sp)[0];
        const float4 x1 = ((const float4*)sp)[1];
        bv = x0.x + x0.y + x0.z + x0.w + x1.x + x1.y + x1.z + x1.w;
        bix = lane;
    }
    #pragma unroll
    for (int off = 8; off; off >>= 1) {
        const float ov = __shfl_down(bv, off);
        const int   oi = __shfl_down(bix, off);
        if (ov > bv || (ov == bv && oi < bix)) { bv = ov; bix = oi; }
    }
    const int bp = __shfl(bix, 0);

    // lanes 0..7: masked softmax of selected path scores
    float sv = 0.f;
    if (lane < L_) sv = sarr[(size_t)g * 128 + bp * 8 + lane];
    float x = sv + (sv == 0.0f ? -9999.0f : 0.0f);
    float m = x;
    #pragma unroll
    for (int off = 4; off; off >>= 1) m = fmaxf(m, __shfl_xor(m, off));
    const float e = expf(x - m);
    float sum = e;
    #pragma unroll
    for (int off = 4; off; off >>= 1) sum += __shfl_xor(sum, off);

    if (lane < L_) {
        const float wr = w_rp[0], wc = w_ch[0], wo = w_on[0];
        const float tw = (t == 0) ? wr : (t == 1) ? wc : (t == 2) ? wo
                                       : (1.0f - wr - wc - wo);
        const float coef = tw * v[lane] * (e / sum);
        wsIdx [g * L_ + lane] = features[(size_t)g * 128 + bp * 8 + lane];
        wsCoef[g * L_ + lane] = coef;
    }
}

// ---------------------------------------------------------------------------
// KF: per (b,i): context = sum of 32 selected rows * coef;
// contextual = [node_emb | context].
// ---------------------------------------------------------------------------
__global__ __launch_bounds__(256) void kf_context(
    const int* __restrict__ nodes, const float* __restrict__ emb,
    const int* __restrict__ wsIdx, const float* __restrict__ wsCoef,
    float* __restrict__ cont)
{
    const int bi  = blockIdx.x;
    const int tid = threadIdx.x;
    float c0 = 0.f, c1 = 0.f;
    #pragma unroll 4
    for (int r = 0; r < 32; ++r) {
        const int   idx = wsIdx [bi * 32 + r];
        const float cf  = wsCoef[bi * 32 + r];
        const float* row = emb + (size_t)idx * D_;
        c0 += cf * row[tid];
        c1 += cf * row[tid + 256];
    }
    const float* nrow = emb + (size_t)nodes[bi] * D_;
    float* cp = cont + (size_t)bi * 1024;
    cp[tid]       = nrow[tid];
    cp[256 + tid] = nrow[tid + 256];
    cp[512 + tid] = c0;
    cp[768 + tid] = c1;
}

// ---------------------------------------------------------------------------
// KG: fused GEMM (contextual @ W_out^T + b_out) + per-b cosine -> sim_ent.
// ---------------------------------------------------------------------------
__global__ __launch_bounds__(256) void kg_gemm_cos(
    const float* __restrict__ cont, const float* __restrict__ W,
    const float* __restrict__ bias, float* __restrict__ out)
{
    const int bb  = blockIdx.x;
    const int tid = threadIdx.x;
    const int wid = tid >> 6, lane = tid & 63;

    __shared__ float cs[8][1024];
    __shared__ float red[4][12];

    for (int k = tid; k < 8 * 1024; k += 256) {
        const int vec = k >> 10, d = k & 1023;
        cs[vec][d] = cont[(size_t)(bb * 8 + vec) * 1024 + d];
    }
    __syncthreads();

    float sab[4] = {0,0,0,0}, saa[4] = {0,0,0,0}, sbb[4] = {0,0,0,0};

    for (int o = wid; o < OUT_; o += 4) {
        const float* wrow = W + (size_t)o * 1024;
        float wv[16];
        #pragma unroll
        for (int k = 0; k < 16; ++k) wv[k] = wrow[lane + 64 * k];
        float dot[8];
        #pragma unroll
        for (int vv = 0; vv < 8; ++vv) {
            float acc = 0.f;
            #pragma unroll
            for (int k = 0; k < 16; ++k) acc += wv[k] * cs[vv][lane + 64 * k];
            dot[vv] = acc;
        }
        #pragma unroll
        for (int vv = 0; vv < 8; ++vv) {
            #pragma unroll
            for (int off = 32; off; off >>= 1) dot[vv] += __shfl_down(dot[vv], off);
        }
        if (lane == 0) {
            const float bo = bias[o];
            #pragma unroll
            for (int j = 0; j < 4; ++j) {
                const float r0 = dot[2*j]   + bo;
                const float r1 = dot[2*j+1] + bo;
                sab[j] += r0 * r1; saa[j] += r0 * r0; sbb[j] += r1 * r1;
            }
        }
    }
    if (lane == 0) {
        #pragma unroll
        for (int j = 0; j < 4; ++j) {
            red[wid][j*3+0] = sab[j];
            red[wid][j*3+1] = saa[j];
            red[wid][j*3+2] = sbb[j];
        }
    }
    __syncthreads();
    if (tid < 4) {
        const int j = tid;
        float ab = 0.f, aa = 0.f, bbv = 0.f;
        for (int w2 = 0; w2 < 4; ++w2) {
            ab  += red[w2][j*3+0];
            aa  += red[w2][j*3+1];
            bbv += red[w2][j*3+2];
        }
        const float na = fmaxf(sqrtf(aa),  1e-8f);
        const float nb = fmaxf(sqrtf(bbv), 1e-8f);
        out[bb * 4 + j] = ab / (na * nb);
    }
}

// ---------------------------------------------------------------------------
// KH1: per (b,j): both sides' aggregates (2x32 rows) + cosine partials.
// ---------------------------------------------------------------------------
__global__ __launch_bounds__(256) void kh1_prop(
    const int* __restrict__ pf, const float* __restrict__ emb,
    float* __restrict__ pprt)
{
    const int bj  = blockIdx.x;            // b*3 + j
    const int b   = bj / 3, j = bj % 3;
    const int tid = threadIdx.x;
    const int wid = tid >> 6, lane = tid & 63;

    float a0 = 0.f, a1 = 0.f, b0 = 0.f, b1 = 0.f;
    const int base0 = ((b * 2 + 0) * 3 + j) * 32;
    const int base1 = ((b * 2 + 1) * 3 + j) * 32;
    #pragma unroll 4
    for (int k = 0; k < 32; ++k) {
        const int idx = pf[base0 + k];
        const float2 r = *(const float2*)(emb + (size_t)idx * D_ + 2 * tid);
        a0 += r.x; a1 += r.y;
    }
    #pragma unroll 4
    for (int k = 0; k < 32; ++k) {
        const int idx = pf[base1 + k];
        const float2 r = *(const float2*)(emb + (size_t)idx * D_ + 2 * tid);
        b0 += r.x; b1 += r.y;
    }
    float pab = a0 * b0 + a1 * b1;
    float paa = a0 * a0 + a1 * a1;
    float pbb = b0 * b0 + b1 * b1;

    __shared__ float red[4][3];
    #pragma unroll
    for (int off = 32; off; off >>= 1) {
        pab += __shfl_down(pab, off);
        paa += __shfl_down(paa, off);
        pbb += __shfl_down(pbb, off);
    }
    if (lane == 0) { red[wid][0] = pab; red[wid][1] = paa; red[wid][2] = pbb; }
    __syncthreads();
    if (tid == 0) {
        pprt[bj * 3 + 0] = red[0][0] + red[1][0] + red[2][0] + red[3][0];
        pprt[bj * 3 + 1] = red[0][1] + red[1][1] + red[2][1] + red[3][1];
        pprt[bj * 3 + 2] = red[0][2] + red[1][2] + red[2][2] + red[3][2];
    }
}

// KH2: combine 3 cosines per b.
__global__ __launch_bounds__(256) void kh2_prop(
    const float* __restrict__ pprt, const float* __restrict__ pw_,
    const float* __restrict__ dw_, float* __restrict__ out)
{
    const int b = blockIdx.x * 256 + threadIdx.x;
    if (b >= B_) return;
    float cosv[3];
    #pragma unroll
    for (int j = 0; j < 3; ++j) {
        const float ab = pprt[(b * 3 + j) * 3 + 0];
        const float aa = pprt[(b * 3 + j) * 3 + 1];
        const float bb = pprt[(b * 3 + j) * 3 + 2];
        const float na = fmaxf(sqrtf(aa), 1e-8f);
        const float nb = fmaxf(sqrtf(bb), 1e-8f);
        cosv[j] = ab / (na * nb);
    }
    const float pw = pw_[0], dw = dw_[0];
    out[B_ + b] = pw * cosv[0] + dw * cosv[1] + (1.0f - pw - dw) * cosv[2];
}

// ---------------------------------------------------------------------------
extern "C" void kernel_launch(void* const* d_in, const int* in_sizes, int n_in,
                              void* d_out, int out_size, void* d_ws, size_t ws_size,
                              hipStream_t stream) {
    const int*   nodes   = (const int*)  d_in[0];
    const int*   features= (const int*)  d_in[1];
    const int*   propf   = (const int*)  d_in[3];
    const float* emb     = (const float*)d_in[4];
    const float* W_out   = (const float*)d_in[5];
    const float* b_out   = (const float*)d_in[6];
    const float* v       = (const float*)d_in[7];
    const float* w_rp    = (const float*)d_in[8];
    const float* w_ch    = (const float*)d_in[9];
    const float* w_on    = (const float*)d_in[10];
    const float* pw      = (const float*)d_in[11];
    const float* dw      = (const float*)d_in[12];
    float* out = (float*)d_out;

    // workspace bump allocation (1KB aligned); total ~11.4 MB (< R1's 12.6 MB use)
    char* ws = (char*)d_ws;
    size_t o = 0;
    auto alloc = [&](size_t bytes) { char* p = ws + o; o += (bytes + 1023) & ~(size_t)1023; return p; };
    int*   counts = (int*)  alloc(V_ * 4);
    int*   offs   = (int*)  alloc((V_ + 1) * 4);
    int*   cursor = (int*)  alloc(V_ * 4);
    int*   bsum   = (int*)  alloc(NSCAN * 4);
    int*   bbase  = (int*)  alloc(NSCAN * 4);
    float* narr   = (float*)alloc((size_t)NBI * D_ * 4);
    int*   inv    = (int*)  alloc((size_t)NSLOT * 4);
    float* sarr   = (float*)alloc((size_t)NSLOT * 4);
    int*   wsIdx  = (int*)  alloc(NG * L_ * 4);
    float* wsCoef = (float*)alloc(NG * L_ * 4);
    float* cont   = (float*)alloc((size_t)NBI * 1024 * 4);
    float* pprt   = (float*)alloc(B_ * 3 * 3 * 4);

    hipMemsetAsync(counts, 0, V_ * 4, stream);
    kn_nodes   <<<NBI,        256, 0, stream>>>(nodes, emb, narr);
    ka_hist    <<<NSLOT/256,  256, 0, stream>>>(features, counts);
    kb1_bsum   <<<NSCAN,      256, 0, stream>>>(counts, bsum);
    kb2_scan   <<<1,          256, 0, stream>>>(bsum, bbase);
    kb3_offsets<<<NSCAN,      256, 0, stream>>>(counts, bbase, offs, cursor);
    kc_scatter <<<NSLOT/256,  256, 0, stream>>>(features, cursor, inv);
    kd_dots    <<<V_/4,       256, 0, stream>>>(emb, narr, offs, inv, sarr);
    ke_select  <<<NG/4,       256, 0, stream>>>(sarr, features, v, w_rp, w_ch, w_on,
                                                wsIdx, wsCoef);
    kf_context <<<NBI,        256, 0, stream>>>(nodes, emb, wsIdx, wsCoef, cont);
    kg_gemm_cos<<<B_/4,       256, 0, stream>>>(cont, W_out, b_out, out);
    kh1_prop   <<<B_*3,       256, 0, stream>>>(propf, emb, pprt);
    kh2_prop   <<<2,          256, 0, stream>>>(pprt, pw, dw, out);
}

// Round 4
// 238.593 us; speedup vs baseline: 1.1378x; 1.0308x over previous
//
#include <hip/hip_runtime.h>
#include <math.h>

#define B_ 512
#define V_ 50000
#define D_ 512
#define T_ 4
#define P_ 16
#define L_ 8
#define OUT_ 300
#define NBI 1024            // B*2
#define NG  4096            // B*2*T
#define NSLOT 524288        // NG*128 (= B*2*T*P*L)
#define NSCAN 196           // ceil(V/256)

// ---------------------------------------------------------------------------
// KN: gather the 1024 node vectors into a contiguous, L2-friendly table.
// ---------------------------------------------------------------------------
__global__ __launch_bounds__(256) void kn_nodes(
    const int* __restrict__ nodes, const float* __restrict__ emb,
    float* __restrict__ narr)
{
    const int bi = blockIdx.x, tid = threadIdx.x;
    const float2 r = *(const float2*)(emb + (size_t)nodes[bi] * D_ + 2 * tid);
    *(float2*)(narr + (size_t)bi * D_ + 2 * tid) = r;
}

// ---------------------------------------------------------------------------
// KA: histogram of feature vocab rows (int atomics -> deterministic counts).
// ---------------------------------------------------------------------------
__global__ __launch_bounds__(256) void ka_hist(
    const int* __restrict__ features, int* __restrict__ counts)
{
    const int slot = blockIdx.x * 256 + threadIdx.x;
    atomicAdd(&counts[features[slot]], 1);
}

// KB1: per-256-chunk sums of counts.
__global__ __launch_bounds__(256) void kb1_bsum(
    const int* __restrict__ counts, int* __restrict__ bsum)
{
    const int tid = threadIdx.x, v = blockIdx.x * 256 + tid;
    const int wid = tid >> 6, lane = tid & 63;
    __shared__ int red[4];
    int c = (v < V_) ? counts[v] : 0;
    #pragma unroll
    for (int off = 32; off; off >>= 1) c += __shfl_down(c, off);
    if (lane == 0) red[wid] = c;
    __syncthreads();
    if (tid == 0) bsum[blockIdx.x] = red[0] + red[1] + red[2] + red[3];
}

// KB2: exclusive scan of the 196 chunk sums (single block).
__global__ __launch_bounds__(256) void kb2_scan(
    const int* __restrict__ bsum, int* __restrict__ bbase)
{
    const int tid = threadIdx.x;
    __shared__ int sc[256];
    const int x = (tid < NSCAN) ? bsum[tid] : 0;
    sc[tid] = x;
    __syncthreads();
    for (int off = 1; off < 256; off <<= 1) {
        const int y = (tid >= off) ? sc[tid - off] : 0;
        __syncthreads();
        sc[tid] += y;
        __syncthreads();
    }
    if (tid < NSCAN) bbase[tid] = sc[tid] - x;   // exclusive
}

// KB3: full exclusive offsets; writes offsets[] and cursor[].
__global__ __launch_bounds__(256) void kb3_offsets(
    const int* __restrict__ counts, const int* __restrict__ bbase,
    int* __restrict__ offs, int* __restrict__ cursor)
{
    const int tid = threadIdx.x, v = blockIdx.x * 256 + tid;
    __shared__ int sc[256];
    const int c = (v < V_) ? counts[v] : 0;
    sc[tid] = c;
    __syncthreads();
    for (int off = 1; off < 256; off <<= 1) {
        const int y = (tid >= off) ? sc[tid - off] : 0;
        __syncthreads();
        sc[tid] += y;
        __syncthreads();
    }
    const int o = bbase[blockIdx.x] + sc[tid] - c;
    if (v < V_) { offs[v] = o; cursor[v] = o; }
    if (v == V_ - 1) offs[V_] = o + c;
}

// KC: scatter slot ids into row-sorted order.
__global__ __launch_bounds__(256) void kc_scatter(
    const int* __restrict__ features, int* __restrict__ cursor,
    int* __restrict__ inv)
{
    const int slot = blockIdx.x * 256 + threadIdx.x;
    const int row  = features[slot];
    const int pos  = atomicAdd(&cursor[row], 1);
    inv[pos] = slot;
}

// ---------------------------------------------------------------------------
// KD: stream emb once; one wave per vocab row; dot against referenced node
// vectors (L2-resident narr); scatter scalar scores to dense s[slot].
// ---------------------------------------------------------------------------
__global__ __launch_bounds__(256) void kd_dots(
    const float* __restrict__ emb, const float* __restrict__ narr,
    const int* __restrict__ offs, const int* __restrict__ inv,
    float* __restrict__ sarr)
{
    const int tid = threadIdx.x;
    const int wid = tid >> 6, lane = tid & 63;
    const int row = blockIdx.x * 4 + wid;          // 12500*4 = 50000 exact

    const float* rp = emb + (size_t)row * D_ + lane * 8;
    const float4 r0 = ((const float4*)rp)[0];
    const float4 r1 = ((const float4*)rp)[1];

    const int st = offs[row], en = offs[row + 1];
    for (int e = st; e < en; e += 2) {
        const int s0 = inv[e];
        const int s1 = (e + 1 < en) ? inv[e + 1] : -1;
        const float* q0 = narr + (size_t)(s0 >> 9) * D_ + lane * 8;
        const float4 a0 = ((const float4*)q0)[0];
        const float4 a1 = ((const float4*)q0)[1];
        float d0 = r0.x*a0.x + r0.y*a0.y + r0.z*a0.z + r0.w*a0.w
                 + r1.x*a1.x + r1.y*a1.y + r1.z*a1.z + r1.w*a1.w;
        float d1 = 0.f;
        if (s1 >= 0) {
            const float* q1 = narr + (size_t)(s1 >> 9) * D_ + lane * 8;
            const float4 b0 = ((const float4*)q1)[0];
            const float4 b1 = ((const float4*)q1)[1];
            d1 = r0.x*b0.x + r0.y*b0.y + r0.z*b0.z + r0.w*b0.w
               + r1.x*b1.x + r1.y*b1.y + r1.z*b1.z + r1.w*b1.w;
        }
        #pragma unroll
        for (int off = 32; off; off >>= 1) {
            d0 += __shfl_down(d0, off);
            d1 += __shfl_down(d1, off);
        }
        if (lane == 0) {
            sarr[s0] = d0;
            if (s1 >= 0) sarr[s1] = d1;
        }
    }
}

// ---------------------------------------------------------------------------
// KE: per g=(bi,t): argmax over P of path sums (first-max), masked softmax
// over L, emit 8 selected row indices + fused coefficients.
// ---------------------------------------------------------------------------
__global__ __launch_bounds__(256) void ke_select(
    const float* __restrict__ sarr, const int* __restrict__ features,
    const float* __restrict__ v, const float* __restrict__ w_rp,
    const float* __restrict__ w_ch, const float* __restrict__ w_on,
    int* __restrict__ wsIdx, float* __restrict__ wsCoef)
{
    const int tid = threadIdx.x;
    const int wid = tid >> 6, lane = tid & 63;
    const int g = blockIdx.x * 4 + wid;
    const int t = g & (T_ - 1);

    // lanes 0..15: pw[p] = sum of 8 scores
    float bv = -1e30f; int bix = 0x7fffffff;
    if (lane < P_) {
        const float* sp = sarr + (size_t)g * 128 + lane * 8;
        const float4 x0 = ((const float4*)sp)[0];
        const float4 x1 = ((const float4*)sp)[1];
        bv = x0.x + x0.y + x0.z + x0.w + x1.x + x1.y + x1.z + x1.w;
        bix = lane;
    }
    #pragma unroll
    for (int off = 8; off; off >>= 1) {
        const float ov = __shfl_down(bv, off);
        const int   oi = __shfl_down(bix, off);
        if (ov > bv || (ov == bv && oi < bix)) { bv = ov; bix = oi; }
    }
    const int bp = __shfl(bix, 0);

    // lanes 0..7: masked softmax of selected path scores
    float sv = 0.f;
    if (lane < L_) sv = sarr[(size_t)g * 128 + bp * 8 + lane];
    float x = sv + (sv == 0.0f ? -9999.0f : 0.0f);
    float m = x;
    #pragma unroll
    for (int off = 4; off; off >>= 1) m = fmaxf(m, __shfl_xor(m, off));
    const float e = expf(x - m);
    float sum = e;
    #pragma unroll
    for (int off = 4; off; off >>= 1) sum += __shfl_xor(sum, off);

    if (lane < L_) {
        const float wr = w_rp[0], wc = w_ch[0], wo = w_on[0];
        const float tw = (t == 0) ? wr : (t == 1) ? wc : (t == 2) ? wo
                                       : (1.0f - wr - wc - wo);
        const float coef = tw * v[lane] * (e / sum);
        wsIdx [g * L_ + lane] = features[(size_t)g * 128 + bp * 8 + lane];
        wsCoef[g * L_ + lane] = coef;
    }
}

// ---------------------------------------------------------------------------
// KF: per (b,i): context = sum of 32 selected rows * coef;
// contextual = [node_emb | context].
// ---------------------------------------------------------------------------
__global__ __launch_bounds__(256) void kf_context(
    const int* __restrict__ nodes, const float* __restrict__ emb,
    const int* __restrict__ wsIdx, const float* __restrict__ wsCoef,
    float* __restrict__ cont)
{
    const int bi  = blockIdx.x;
    const int tid = threadIdx.x;
    float c0 = 0.f, c1 = 0.f;
    #pragma unroll 4
    for (int r = 0; r < 32; ++r) {
        const int   idx = wsIdx [bi * 32 + r];
        const float cf  = wsCoef[bi * 32 + r];
        const float* row = emb + (size_t)idx * D_;
        c0 += cf * row[tid];
        c1 += cf * row[tid + 256];
    }
    const float* nrow = emb + (size_t)nodes[bi] * D_;
    float* cp = cont + (size_t)bi * 1024;
    cp[tid]       = nrow[tid];
    cp[256 + tid] = nrow[tid + 256];
    cp[512 + tid] = c0;
    cp[768 + tid] = c1;
}

// ---------------------------------------------------------------------------
// KW: transpose W (300x1024) -> Wtv[k4][o] float4-over-k, stride OUT_.
// ---------------------------------------------------------------------------
__global__ __launch_bounds__(256) void kw_transpose(
    const float* __restrict__ W, float4* __restrict__ Wtv)
{
    const int o  = blockIdx.x;       // 0..299
    const int k4 = threadIdx.x;      // 0..255
    const float4 w = *(const float4*)(W + (size_t)o * 1024 + 4 * k4);
    Wtv[(size_t)k4 * OUT_ + o] = w;
}

// ---------------------------------------------------------------------------
// KG: output-stationary GEMM + fused cosine. One block per 2 b's (4 vectors
// staged k-major in LDS); each thread owns output column o = tid (+256);
// no shuffles in the hot loop; W reads coalesced along o.
// ---------------------------------------------------------------------------
__global__ __launch_bounds__(256) void kg_gemm_cos(
    const float* __restrict__ cont, const float4* __restrict__ Wtv,
    const float* __restrict__ bias, float* __restrict__ out)
{
    const int bb  = blockIdx.x;       // b0 = 2bb, b1 = 2bb+1; vecs 4bb..4bb+3
    const int tid = threadIdx.x;
    const int wid = tid >> 6, lane = tid & 63;

    __shared__ float4 cs[1024];       // cs[k] = {v0[k],v1[k],v2[k],v3[k]} 16KB
    __shared__ float  red[4][6];

    const float* cb = cont + (size_t)bb * 4 * 1024;
    for (int idx = tid; idx < 4096; idx += 256) {
        const int vv = idx & 3, k = idx >> 2;
        ((float*)&cs[k])[vv] = cb[vv * 1024 + k];
    }
    __syncthreads();

    float p[6] = {0,0,0,0,0,0};
    #pragma unroll
    for (int pass = 0; pass < 2; ++pass) {
        const int o = tid + pass * 256;
        if (o < OUT_) {
            float4 acc = {0,0,0,0};
            const float4* wp = Wtv + o;
            #pragma unroll 4
            for (int k4 = 0; k4 < 256; ++k4) {
                const float4 wv = wp[(size_t)k4 * OUT_];
                const float4 c0 = cs[4*k4+0];
                const float4 c1 = cs[4*k4+1];
                const float4 c2 = cs[4*k4+2];
                const float4 c3 = cs[4*k4+3];
                acc.x += c0.x*wv.x + c1.x*wv.y + c2.x*wv.z + c3.x*wv.w;
                acc.y += c0.y*wv.x + c1.y*wv.y + c2.y*wv.z + c3.y*wv.w;
                acc.z += c0.z*wv.x + c1.z*wv.y + c2.z*wv.z + c3.z*wv.w;
                acc.w += c0.w*wv.x + c1.w*wv.y + c2.w*wv.z + c3.w*wv.w;
            }
            const float bo = bias[o];
            const float r0 = acc.x + bo, r1 = acc.y + bo;
            const float r2 = acc.z + bo, r3 = acc.w + bo;
            p[0] += r0 * r1; p[1] += r0 * r0; p[2] += r1 * r1;
            p[3] += r2 * r3; p[4] += r2 * r2; p[5] += r3 * r3;
        }
    }
    #pragma unroll
    for (int q = 0; q < 6; ++q) {
        #pragma unroll
        for (int off = 32; off; off >>= 1) p[q] += __shfl_down(p[q], off);
    }
    if (lane == 0) {
        #pragma unroll
        for (int q = 0; q < 6; ++q) red[wid][q] = p[q];
    }
    __syncthreads();
    if (tid < 2) {
        const int j = tid;
        float ab = 0.f, aa = 0.f, bbv = 0.f;
        #pragma unroll
        for (int w2 = 0; w2 < 4; ++w2) {
            ab  += red[w2][j*3+0];
            aa  += red[w2][j*3+1];
            bbv += red[w2][j*3+2];
        }
        const float na = fmaxf(sqrtf(aa),  1e-8f);
        const float nb = fmaxf(sqrtf(bbv), 1e-8f);
        out[bb * 2 + j] = ab / (na * nb);
    }
}

// ---------------------------------------------------------------------------
// KH1: per (b,j): both sides' aggregates (2x32 rows) + cosine partials.
// ---------------------------------------------------------------------------
__global__ __launch_bounds__(256) void kh1_prop(
    const int* __restrict__ pf, const float* __restrict__ emb,
    float* __restrict__ pprt)
{
    const int bj  = blockIdx.x;            // b*3 + j
    const int b   = bj / 3, j = bj % 3;
    const int tid = threadIdx.x;
    const int wid = tid >> 6, lane = tid & 63;

    float a0 = 0.f, a1 = 0.f, b0 = 0.f, b1 = 0.f;
    const int base0 = ((b * 2 + 0) * 3 + j) * 32;
    const int base1 = ((b * 2 + 1) * 3 + j) * 32;
    #pragma unroll 4
    for (int k = 0; k < 32; ++k) {
        const int idx = pf[base0 + k];
        const float2 r = *(const float2*)(emb + (size_t)idx * D_ + 2 * tid);
        a0 += r.x; a1 += r.y;
    }
    #pragma unroll 4
    for (int k = 0; k < 32; ++k) {
        const int idx = pf[base1 + k];
        const float2 r = *(const float2*)(emb + (size_t)idx * D_ + 2 * tid);
        b0 += r.x; b1 += r.y;
    }
    float pab = a0 * b0 + a1 * b1;
    float paa = a0 * a0 + a1 * a1;
    float pbb = b0 * b0 + b1 * b1;

    __shared__ float red[4][3];
    #pragma unroll
    for (int off = 32; off; off >>= 1) {
        pab += __shfl_down(pab, off);
        paa += __shfl_down(paa, off);
        pbb += __shfl_down(pbb, off);
    }
    if (lane == 0) { red[wid][0] = pab; red[wid][1] = paa; red[wid][2] = pbb; }
    __syncthreads();
    if (tid == 0) {
        pprt[bj * 3 + 0] = red[0][0] + red[1][0] + red[2][0] + red[3][0];
        pprt[bj * 3 + 1] = red[0][1] + red[1][1] + red[2][1] + red[3][1];
        pprt[bj * 3 + 2] = red[0][2] + red[1][2] + red[2][2] + red[3][2];
    }
}

// KH2: combine 3 cosines per b.
__global__ __launch_bounds__(256) void kh2_prop(
    const float* __restrict__ pprt, const float* __restrict__ pw_,
    const float* __restrict__ dw_, float* __restrict__ out)
{
    const int b = blockIdx.x * 256 + threadIdx.x;
    if (b >= B_) return;
    float cosv[3];
    #pragma unroll
    for (int j = 0; j < 3; ++j) {
        const float ab = pprt[(b * 3 + j) * 3 + 0];
        const float aa = pprt[(b * 3 + j) * 3 + 1];
        const float bb = pprt[(b * 3 + j) * 3 + 2];
        const float na = fmaxf(sqrtf(aa), 1e-8f);
        const float nb = fmaxf(sqrtf(bb), 1e-8f);
        cosv[j] = ab / (na * nb);
    }
    const float pw = pw_[0], dw = dw_[0];
    out[B_ + b] = pw * cosv[0] + dw * cosv[1] + (1.0f - pw - dw) * cosv[2];
}

// ---------------------------------------------------------------------------
extern "C" void kernel_launch(void* const* d_in, const int* in_sizes, int n_in,
                              void* d_out, int out_size, void* d_ws, size_t ws_size,
                              hipStream_t stream) {
    const int*   nodes   = (const int*)  d_in[0];
    const int*   features= (const int*)  d_in[1];
    const int*   propf   = (const int*)  d_in[3];
    const float* emb     = (const float*)d_in[4];
    const float* W_out   = (const float*)d_in[5];
    const float* b_out   = (const float*)d_in[6];
    const float* v       = (const float*)d_in[7];
    const float* w_rp    = (const float*)d_in[8];
    const float* w_ch    = (const float*)d_in[9];
    const float* w_on    = (const float*)d_in[10];
    const float* pw      = (const float*)d_in[11];
    const float* dw      = (const float*)d_in[12];
    float* out = (float*)d_out;

    // workspace bump allocation (1KB aligned); total ~12.2 MB
    char* ws = (char*)d_ws;
    size_t o = 0;
    auto alloc = [&](size_t bytes) { char* p = ws + o; o += (bytes + 1023) & ~(size_t)1023; return p; };
    int*   counts = (int*)  alloc(V_ * 4);
    int*   offs   = (int*)  alloc((V_ + 1) * 4);
    int*   cursor = (int*)  alloc(V_ * 4);
    int*   bsum   = (int*)  alloc(NSCAN * 4);
    int*   bbase  = (int*)  alloc(NSCAN * 4);
    float* narr   = (float*)alloc((size_t)NBI * D_ * 4);
    int*   inv    = (int*)  alloc((size_t)NSLOT * 4);
    float* sarr   = (float*)alloc((size_t)NSLOT * 4);
    int*   wsIdx  = (int*)  alloc(NG * L_ * 4);
    float* wsCoef = (float*)alloc(NG * L_ * 4);
    float* cont   = (float*)alloc((size_t)NBI * 1024 * 4);
    float* pprt   = (float*)alloc(B_ * 3 * 3 * 4);
    float4* Wtv   = (float4*)alloc((size_t)256 * OUT_ * 16);

    hipMemsetAsync(counts, 0, V_ * 4, stream);
    kn_nodes    <<<NBI,        256, 0, stream>>>(nodes, emb, narr);
    kw_transpose<<<OUT_,       256, 0, stream>>>(W_out, Wtv);
    ka_hist     <<<NSLOT/256,  256, 0, stream>>>(features, counts);
    kb1_bsum    <<<NSCAN,      256, 0, stream>>>(counts, bsum);
    kb2_scan    <<<1,          256, 0, stream>>>(bsum, bbase);
    kb3_offsets <<<NSCAN,      256, 0, stream>>>(counts, bbase, offs, cursor);
    kc_scatter  <<<NSLOT/256,  256, 0, stream>>>(features, cursor, inv);
    kd_dots     <<<V_/4,       256, 0, stream>>>(emb, narr, offs, inv, sarr);
    ke_select   <<<NG/4,       256, 0, stream>>>(sarr, features, v, w_rp, w_ch, w_on,
                                                 wsIdx, wsCoef);
    kf_context  <<<NBI,        256, 0, stream>>>(nodes, emb, wsIdx, wsCoef, cont);
    kg_gemm_cos <<<B_/2,       256, 0, stream>>>(cont, Wtv, b_out, out);
    kh1_prop    <<<B_*3,       256, 0, stream>>>(propf, emb, pprt);
    kh2_prop    <<<2,          256, 0, stream>>>(pprt, pw, dw, out);
}